// Round 1
// baseline (275.562 us; speedup 1.0000x reference)
//
#include <hip/hip_runtime.h>

#define HS 64          // head size
#define NE 1024        // n_embd
#define TT 2048        // sequence length
#define BATCH 8
#define MROWS (BATCH*TT)   // 16384

// ---------------------------------------------------------------------------
// Projection: [M,1024] x [1024,192] -> q,k,v  (fp32, LDS-tiled)
// grid = M/64 blocks, 256 threads. Thread tile: 4 rows x 12 cols.
// ---------------------------------------------------------------------------
__global__ __launch_bounds__(256) void proj_kernel(
    const float* __restrict__ x,
    const float* __restrict__ Wk,
    const float* __restrict__ Wq,
    const float* __restrict__ Wv,
    float* __restrict__ qp, float* __restrict__ kp, float* __restrict__ vp)
{
    __shared__ float xs[64][36];    // 64 rows x 32 k, stride 36 (f4-aligned, 2-way banks)
    __shared__ float wsh[32][196];  // 32 k x 192 cols (q|k|v), stride 196

    const int tid = threadIdx.x;
    const int ty  = tid >> 4;   // 0..15 -> rows ty*4..+3
    const int tx  = tid & 15;   // 0..15 -> cols tx*12..+11
    const int row0 = blockIdx.x * 64;

    float acc[4][12];
    #pragma unroll
    for (int i = 0; i < 4; i++)
        #pragma unroll
        for (int j = 0; j < 12; j++) acc[i][j] = 0.f;

    for (int c0 = 0; c0 < NE; c0 += 32) {
        __syncthreads();
        // stage x tile: 64x32 = 512 float4, 2 per thread
        #pragma unroll
        for (int t = 0; t < 2; t++) {
            int f  = tid + t * 256;
            int r  = f >> 3;
            int i4 = f & 7;
            float4 v = *(const float4*)(x + (size_t)(row0 + r) * NE + c0 + i4 * 4);
            *(float4*)&xs[r][i4 * 4] = v;
        }
        // stage W tile: 32x192 = 1536 float4, 6 per thread. logical cols: 0-63 q, 64-127 k, 128-191 v
        #pragma unroll
        for (int t = 0; t < 6; t++) {
            int f   = tid + t * 256;
            int r   = f / 48;
            int i4  = f % 48;
            int mat = i4 >> 4;
            int h4  = i4 & 15;
            const float* Wsrc = (mat == 0) ? Wq : ((mat == 1) ? Wk : Wv);
            float4 v = *(const float4*)(Wsrc + (size_t)(c0 + r) * HS + h4 * 4);
            *(float4*)&wsh[r][mat * 64 + h4 * 4] = v;
        }
        __syncthreads();

        #pragma unroll 2
        for (int kk = 0; kk < 32; kk++) {
            float xr[4];
            #pragma unroll
            for (int i = 0; i < 4; i++) xr[i] = xs[ty * 4 + i][kk];
            float wr[12];
            #pragma unroll
            for (int j4 = 0; j4 < 3; j4++) {
                float4 w4 = *(const float4*)&wsh[kk][tx * 12 + j4 * 4];
                wr[j4 * 4 + 0] = w4.x; wr[j4 * 4 + 1] = w4.y;
                wr[j4 * 4 + 2] = w4.z; wr[j4 * 4 + 3] = w4.w;
            }
            #pragma unroll
            for (int i = 0; i < 4; i++)
                #pragma unroll
                for (int j = 0; j < 12; j++)
                    acc[i][j] = fmaf(xr[i], wr[j], acc[i][j]);
        }
    }

    // write out (scalar; cols may straddle the q/k/v boundary)
    #pragma unroll
    for (int i = 0; i < 4; i++) {
        size_t rbase = (size_t)(row0 + ty * 4 + i) * HS;
        #pragma unroll
        for (int j = 0; j < 12; j++) {
            int h   = tx * 12 + j;
            int mat = h >> 6;
            int hh  = h & 63;
            float* dst = (mat == 0) ? qp : ((mat == 1) ? kp : vp);
            dst[rbase + hh] = acc[i][j];
        }
    }
}

// ---------------------------------------------------------------------------
// Flash attention (fp32): 32 q-rows/block, 64-wide kv tiles, online softmax.
// grid = 8*64 = 512 blocks, 256 threads. Thread tile: 2 q-rows x 4 cols.
// ---------------------------------------------------------------------------
#define QB 32
__global__ __launch_bounds__(256) void attn_kernel(
    const float* __restrict__ qp, const float* __restrict__ kp,
    const float* __restrict__ vp, float* __restrict__ out)
{
    __shared__ float qs[QB][68];
    __shared__ float ps[QB][68];
    __shared__ float ks[64][64];   // XOR-swizzled at float4 granularity
    __shared__ float vs[64][68];

    const int tid = threadIdx.x;
    const int ty  = tid >> 4;            // 0..15 -> q-rows ty*2..+1
    const int tx  = tid & 15;            // 0..15 -> cols tx*4..+3
    const int b   = blockIdx.x >> 6;     // batch
    const int qt  = blockIdx.x & 63;     // q tile
    const int r0  = qt * QB;

    const float* qb = qp + (size_t)b * TT * HS;
    const float* kb = kp + (size_t)b * TT * HS;
    const float* vb = vp + (size_t)b * TT * HS;

    // stage q tile: 32x64 = 512 float4, 2 per thread
    #pragma unroll
    for (int t = 0; t < 2; t++) {
        int f  = tid + t * 256;
        int r  = f >> 4;
        int i4 = f & 15;
        *(float4*)&qs[r][i4 * 4] = *(const float4*)(qb + (size_t)(r0 + r) * HS + i4 * 4);
    }

    float m[2]      = { -INFINITY, -INFINITY };
    float l[2]      = { 0.f, 0.f };
    float acc[2][4] = {};

    const int nkv = (r0 + QB - 1) / 64 + 1;
    for (int kt = 0; kt < nkv; kt++) {
        const int s0 = kt * 64;
        __syncthreads();   // prev iteration fully done (incl. first-iter q staging fence below)
        // stage k (swizzled) + v: 1024 f4 each, 4 per thread each
        #pragma unroll
        for (int t = 0; t < 4; t++) {
            int f = tid + t * 256;
            int r = f >> 4;
            int g = f & 15;
            float4 k4 = *(const float4*)(kb + (size_t)(s0 + r) * HS + g * 4);
            int gs = (g ^ (r >> 2)) & 15;
            *(float4*)&ks[r][gs * 4] = k4;
            float4 v4 = *(const float4*)(vb + (size_t)(s0 + r) * HS + g * 4);
            *(float4*)&vs[r][g * 4] = v4;
        }
        __syncthreads();

        // S = q @ k^T  (2x4 per thread)
        float sacc[2][4] = {};
        #pragma unroll
        for (int d4 = 0; d4 < 16; d4++) {
            float4 q4[2];
            q4[0] = *(const float4*)&qs[ty * 2 + 0][d4 * 4];
            q4[1] = *(const float4*)&qs[ty * 2 + 1][d4 * 4];
            #pragma unroll
            for (int j = 0; j < 4; j++) {
                int kr = tx * 4 + j;
                float4 k4 = *(const float4*)&ks[kr][((d4 ^ (kr >> 2)) & 15) * 4];
                #pragma unroll
                for (int i = 0; i < 2; i++) {
                    sacc[i][j] = fmaf(q4[i].x, k4.x, sacc[i][j]);
                    sacc[i][j] = fmaf(q4[i].y, k4.y, sacc[i][j]);
                    sacc[i][j] = fmaf(q4[i].z, k4.z, sacc[i][j]);
                    sacc[i][j] = fmaf(q4[i].w, k4.w, sacc[i][j]);
                }
            }
        }

        // scale + causal mask (only the final tile can touch the diagonal)
        const float scale = 0.03125f;  // 1024^-0.5
        const bool need_mask = (kt == nkv - 1);
        float tm[2] = { -INFINITY, -INFINITY };
        #pragma unroll
        for (int i = 0; i < 2; i++) {
            int grow = r0 + ty * 2 + i;
            #pragma unroll
            for (int j = 0; j < 4; j++) {
                int gcol = s0 + tx * 4 + j;
                float sv = sacc[i][j] * scale;
                if (need_mask && gcol > grow) sv = -INFINITY;
                sacc[i][j] = sv;
                tm[i] = fmaxf(tm[i], sv);
            }
        }
        #pragma unroll
        for (int off = 1; off < 16; off <<= 1) {
            tm[0] = fmaxf(tm[0], __shfl_xor(tm[0], off, 64));
            tm[1] = fmaxf(tm[1], __shfl_xor(tm[1], off, 64));
        }

        float alpha[2], p_sum[2];
        #pragma unroll
        for (int i = 0; i < 2; i++) {
            float mnew = fmaxf(m[i], tm[i]);
            alpha[i]   = __expf(m[i] - mnew);   // first tile: exp(-inf) = 0
            m[i]       = mnew;
            float s = 0.f;
            #pragma unroll
            for (int j = 0; j < 4; j++) {
                float p = __expf(sacc[i][j] - mnew);  // masked: exp(-inf) = 0
                sacc[i][j] = p;
                s += p;
            }
            p_sum[i] = s;
        }
        #pragma unroll
        for (int off = 1; off < 16; off <<= 1) {
            p_sum[0] += __shfl_xor(p_sum[0], off, 64);
            p_sum[1] += __shfl_xor(p_sum[1], off, 64);
        }
        #pragma unroll
        for (int i = 0; i < 2; i++) {
            l[i] = l[i] * alpha[i] + p_sum[i];
            #pragma unroll
            for (int d = 0; d < 4; d++) acc[i][d] *= alpha[i];
        }

        // P to LDS
        #pragma unroll
        for (int i = 0; i < 2; i++) {
            float4 pv = make_float4(sacc[i][0], sacc[i][1], sacc[i][2], sacc[i][3]);
            *(float4*)&ps[ty * 2 + i][tx * 4] = pv;
        }
        __syncthreads();

        // acc += P @ V
        #pragma unroll
        for (int j4 = 0; j4 < 16; j4++) {
            float4 p4[2];
            p4[0] = *(const float4*)&ps[ty * 2 + 0][j4 * 4];
            p4[1] = *(const float4*)&ps[ty * 2 + 1][j4 * 4];
            #pragma unroll
            for (int jj = 0; jj < 4; jj++) {
                float4 v4 = *(const float4*)&vs[j4 * 4 + jj][tx * 4];
                float pj0 = ((const float*)&p4[0])[jj];
                float pj1 = ((const float*)&p4[1])[jj];
                acc[0][0] = fmaf(pj0, v4.x, acc[0][0]);
                acc[0][1] = fmaf(pj0, v4.y, acc[0][1]);
                acc[0][2] = fmaf(pj0, v4.z, acc[0][2]);
                acc[0][3] = fmaf(pj0, v4.w, acc[0][3]);
                acc[1][0] = fmaf(pj1, v4.x, acc[1][0]);
                acc[1][1] = fmaf(pj1, v4.y, acc[1][1]);
                acc[1][2] = fmaf(pj1, v4.z, acc[1][2]);
                acc[1][3] = fmaf(pj1, v4.w, acc[1][3]);
            }
        }
    }

    // epilogue: out = acc / l
    #pragma unroll
    for (int i = 0; i < 2; i++) {
        float inv = 1.0f / l[i];
        float4 o = make_float4(acc[i][0] * inv, acc[i][1] * inv,
                               acc[i][2] * inv, acc[i][3] * inv);
        *(float4*)(out + ((size_t)b * TT + r0 + ty * 2 + i) * HS + tx * 4) = o;
    }
}

extern "C" void kernel_launch(void* const* d_in, const int* in_sizes, int n_in,
                              void* d_out, int out_size, void* d_ws, size_t ws_size,
                              hipStream_t stream) {
    const float* x  = (const float*)d_in[0];
    const float* Wk = (const float*)d_in[1];
    const float* Wq = (const float*)d_in[2];
    const float* Wv = (const float*)d_in[3];
    float* outp = (float*)d_out;

    float* qp = (float*)d_ws;                       // [16384][64]
    float* kp = qp + (size_t)MROWS * HS;
    float* vp = kp + (size_t)MROWS * HS;            // total 12 MB

    proj_kernel<<<MROWS / 64, 256, 0, stream>>>(x, Wk, Wq, Wv, qp, kp, vp);
    attn_kernel<<<BATCH * (TT / QB), 256, 0, stream>>>(qp, kp, vp, outp);
}

// Round 2
// 114.002 us; speedup vs baseline: 2.4172x; 2.4172x over previous
//
#include <hip/hip_runtime.h>
#include <hip/hip_bf16.h>

#define TT 2048
#define BATCH 8
#define MROWS (BATCH*TT)   // 16384

typedef __attribute__((ext_vector_type(8))) short bf16x8;   // MFMA A/B frag (4 VGPR)
typedef __attribute__((ext_vector_type(4))) short s16x4;
typedef __attribute__((ext_vector_type(4))) float f32x4;    // MFMA C/D frag

__device__ __forceinline__ short f2bf(float f) {
    union { __hip_bfloat16 h; short s; } u;
    u.h = __float2bfloat16(f);
    return u.s;
}

// ---------------------------------------------------------------------------
// W transpose: Wq|Wk|Wv [1024][64] f32 -> wt [192][1024] bf16 (row n = col of W)
// Wq gets scale = (1/32)*log2(e) folded in (softmax scale + exp->exp2).
// grid = 48 blocks (3 mats x 16 k-tiles), 256 threads.
// ---------------------------------------------------------------------------
__global__ __launch_bounds__(256) void wtrans_kernel(
    const float* __restrict__ Wk, const float* __restrict__ Wq,
    const float* __restrict__ Wv, short* __restrict__ wt)
{
    __shared__ float tile[64][68];
    const int mat = blockIdx.x >> 4;           // 0=q,1=k,2=v
    const int k0  = (blockIdx.x & 15) * 64;
    const float* W = (mat == 0) ? Wq : (mat == 1) ? Wk : Wv;
    const float scl = (mat == 0) ? 0.04508422002778011f : 1.0f;  // (1/32)*log2(e)
    const int t = threadIdx.x;
    const int row = t >> 2, quad = t & 3;
    #pragma unroll
    for (int i = 0; i < 4; i++) {
        float4 v = *(const float4*)(W + (size_t)(k0 + row) * 64 + quad * 16 + i * 4);
        *(float4*)&tile[row][quad * 16 + i * 4] = v;
    }
    __syncthreads();
    short tmp[16];
    #pragma unroll
    for (int j = 0; j < 16; j++) tmp[j] = f2bf(tile[quad * 16 + j][row] * scl);
    short* dst = wt + (size_t)(mat * 64 + row) * 1024 + k0 + quad * 16;
    #pragma unroll
    for (int j2 = 0; j2 < 2; j2++) {
        bf16x8 o;
        #pragma unroll
        for (int jj = 0; jj < 8; jj++) o[jj] = tmp[j2 * 8 + jj];
        *(bf16x8*)(dst + j2 * 8) = o;
    }
}

// ---------------------------------------------------------------------------
// Projection: x[16384][1024] f32 -> q,k [16384][64] bf16, v^T [8][64][2048] bf16
// 64-row blocks, 4 waves, wave w owns cols [w*48, w*48+48). MFMA 16x16x32 bf16.
// x staged to LDS bf16 (double-buffered); W frags direct from L2-resident wt.
// ---------------------------------------------------------------------------
__global__ __launch_bounds__(256) void proj_kernel(
    const float* __restrict__ x, const short* __restrict__ wt,
    short* __restrict__ qb, short* __restrict__ kb, short* __restrict__ vtb)
{
    __shared__ short xs[2][64][72];
    __shared__ short vsl[64][66];
    const int tid  = threadIdx.x;
    const int lane = tid & 63, w = tid >> 6;
    const int l15  = lane & 15, g = lane >> 4;
    const int r0   = blockIdx.x * 64;
    const int xrow = tid >> 2, xquad = tid & 3;

    f32x4 acc[4][3];
    #pragma unroll
    for (int rt = 0; rt < 4; rt++)
        #pragma unroll
        for (int nt = 0; nt < 3; nt++)
            acc[rt][nt] = (f32x4){0.f, 0.f, 0.f, 0.f};

    const float* xbase = x + (size_t)(r0 + xrow) * 1024 + xquad * 16;

    // prologue: stage k-tile 0 into buffer 0
    float4 xr[4];
    #pragma unroll
    for (int i = 0; i < 4; i++) xr[i] = *(const float4*)(xbase + i * 4);
    #pragma unroll
    for (int i = 0; i < 4; i++) {
        s16x4 s = { f2bf(xr[i].x), f2bf(xr[i].y), f2bf(xr[i].z), f2bf(xr[i].w) };
        *(s16x4*)&xs[0][xrow][xquad * 16 + i * 4] = s;
    }

    int cur = 0;
    for (int ks = 0; ks < 16; ks++) {
        const int k0 = ks * 64;
        if (ks < 15) {   // issue next x tile loads early (latency hides under MFMA)
            #pragma unroll
            for (int i = 0; i < 4; i++) xr[i] = *(const float4*)(xbase + k0 + 64 + i * 4);
        }
        // B frags direct from global (L2-resident wt)
        bf16x8 bfrag[3][2];
        #pragma unroll
        for (int nt = 0; nt < 3; nt++)
            #pragma unroll
            for (int kc = 0; kc < 2; kc++)
                bfrag[nt][kc] = *(const bf16x8*)(
                    wt + (size_t)(w * 48 + nt * 16 + l15) * 1024 + k0 + kc * 32 + g * 8);
        __syncthreads();
        #pragma unroll
        for (int kc = 0; kc < 2; kc++) {
            bf16x8 af[4];
            #pragma unroll
            for (int rt = 0; rt < 4; rt++)
                af[rt] = *(const bf16x8*)&xs[cur][rt * 16 + l15][kc * 32 + g * 8];
            #pragma unroll
            for (int rt = 0; rt < 4; rt++)
                #pragma unroll
                for (int nt = 0; nt < 3; nt++)
                    acc[rt][nt] = __builtin_amdgcn_mfma_f32_16x16x32_bf16(
                        af[rt], bfrag[nt][kc], acc[rt][nt], 0, 0, 0);
        }
        if (ks < 15) {   // write next tile into the other buffer (no extra barrier)
            #pragma unroll
            for (int i = 0; i < 4; i++) {
                s16x4 s = { f2bf(xr[i].x), f2bf(xr[i].y), f2bf(xr[i].z), f2bf(xr[i].w) };
                *(s16x4*)&xs[cur ^ 1][xrow][xquad * 16 + i * 4] = s;
            }
        }
        cur ^= 1;
    }

    // epilogue: q,k direct; v staged to LDS for transposed coalesced write
    const int bi  = r0 >> 11;       // batch
    const int sl0 = r0 & 2047;      // seq offset within batch
    #pragma unroll
    for (int rt = 0; rt < 4; rt++)
        #pragma unroll
        for (int nt = 0; nt < 3; nt++) {
            const int c = w * 48 + nt * 16 + l15;
            #pragma unroll
            for (int r = 0; r < 4; r++) {
                const int row = r0 + rt * 16 + g * 4 + r;
                const short v = f2bf(acc[rt][nt][r]);
                if (c < 64)        qb[(size_t)row * 64 + c] = v;
                else if (c < 128)  kb[(size_t)row * 64 + (c - 64)] = v;
                else               vsl[rt * 16 + g * 4 + r][c - 128] = v;
            }
        }
    __syncthreads();
    {   // vt[b][h][seq] cooperative write: thread owns (h, 16-seq segment)
        const int h = tid >> 2, seg = tid & 3;
        short tmp[16];
        #pragma unroll
        for (int j = 0; j < 16; j++) tmp[j] = vsl[seg * 16 + j][h];
        short* dst = vtb + ((size_t)bi * 64 + h) * TT + sl0 + seg * 16;
        #pragma unroll
        for (int j2 = 0; j2 < 2; j2++) {
            bf16x8 o;
            #pragma unroll
            for (int jj = 0; jj < 8; jj++) o[jj] = tmp[j2 * 8 + jj];
            *(bf16x8*)(dst + j2 * 8) = o;
        }
    }
}

// ---------------------------------------------------------------------------
// Flash attention, MFMA bf16. One wave (64 thr) per block = one 32-row q-tile.
// grid = 8*64 = 512 blocks, longest-work-first order. K/V frags direct from L2
// (no barriers anywhere); P transposed through padded LDS. exp2-space softmax.
// ---------------------------------------------------------------------------
__global__ __launch_bounds__(64) void attn_kernel(
    const short* __restrict__ qb, const short* __restrict__ kb,
    const short* __restrict__ vtb, float* __restrict__ out)
{
    __shared__ short ps[32][72];
    const int widx = blockIdx.x;
    const int b    = widx & 7;
    const int qt   = 63 - (widx >> 3);    // descending work order
    const int r0   = qt * 32;
    const int lane = threadIdx.x & 63;
    const int l15  = lane & 15, g = lane >> 4;

    const short* q  = qb  + (size_t)b * TT * 64;
    const short* k  = kb  + (size_t)b * TT * 64;
    const short* vt = vtb + (size_t)b * 64 * TT;

    // Q frags, held in registers for the whole kernel
    bf16x8 qf[2][2];
    #pragma unroll
    for (int rt = 0; rt < 2; rt++)
        #pragma unroll
        for (int kc = 0; kc < 2; kc++)
            qf[rt][kc] = *(const bf16x8*)(q + (size_t)(r0 + rt * 16 + l15) * 64 + kc * 32 + g * 8);

    f32x4 o[2][4];
    float m_[2][4], l_[2][4];
    #pragma unroll
    for (int rt = 0; rt < 2; rt++) {
        #pragma unroll
        for (int ht = 0; ht < 4; ht++) o[rt][ht] = (f32x4){0.f, 0.f, 0.f, 0.f};
        #pragma unroll
        for (int r = 0; r < 4; r++) { m_[rt][r] = -INFINITY; l_[rt][r] = 0.f; }
    }

    const int nkv = (r0 >> 6) + 1;

    bf16x8 kf[4][2];
    #pragma unroll
    for (int nt = 0; nt < 4; nt++)
        #pragma unroll
        for (int kc = 0; kc < 2; kc++)
            kf[nt][kc] = *(const bf16x8*)(k + (size_t)(nt * 16 + l15) * 64 + kc * 32 + g * 8);

    for (int kt = 0; kt < nkv; kt++) {
        const int s0 = kt * 64;

        // S = Q K^T
        f32x4 s[2][4];
        #pragma unroll
        for (int rt = 0; rt < 2; rt++)
            #pragma unroll
            for (int nt = 0; nt < 4; nt++)
                s[rt][nt] = (f32x4){0.f, 0.f, 0.f, 0.f};
        #pragma unroll
        for (int kc = 0; kc < 2; kc++)
            #pragma unroll
            for (int rt = 0; rt < 2; rt++)
                #pragma unroll
                for (int nt = 0; nt < 4; nt++)
                    s[rt][nt] = __builtin_amdgcn_mfma_f32_16x16x32_bf16(
                        qf[rt][kc], kf[nt][kc], s[rt][nt], 0, 0, 0);

        // issue V frags (this tile) + next K frags early; latency hides under softmax
        bf16x8 vf[4][2];
        #pragma unroll
        for (int ht = 0; ht < 4; ht++)
            #pragma unroll
            for (int jc = 0; jc < 2; jc++)
                vf[ht][jc] = *(const bf16x8*)(vt + (size_t)(ht * 16 + l15) * TT + s0 + jc * 32 + g * 8);
        bf16x8 kfn[4][2];
        if (kt + 1 < nkv) {
            #pragma unroll
            for (int nt = 0; nt < 4; nt++)
                #pragma unroll
                for (int kc = 0; kc < 2; kc++)
                    kfn[nt][kc] = *(const bf16x8*)(
                        k + (size_t)(s0 + 64 + nt * 16 + l15) * 64 + kc * 32 + g * 8);
        }

        // causal mask: only the diagonal tile needs it
        if (kt == nkv - 1) {
            #pragma unroll
            for (int rt = 0; rt < 2; rt++)
                #pragma unroll
                for (int nt = 0; nt < 4; nt++) {
                    const int col = s0 + nt * 16 + l15;
                    #pragma unroll
                    for (int r = 0; r < 4; r++) {
                        const int row = r0 + rt * 16 + g * 4 + r;
                        if (col > row) s[rt][nt][r] = -INFINITY;
                    }
                }
        }

        // online softmax (exp2 space; scale folded into Wq)
        #pragma unroll
        for (int rt = 0; rt < 2; rt++) {
            #pragma unroll
            for (int r = 0; r < 4; r++) {
                float tm = fmaxf(fmaxf(s[rt][0][r], s[rt][1][r]),
                                 fmaxf(s[rt][2][r], s[rt][3][r]));
                #pragma unroll
                for (int off = 1; off < 16; off <<= 1)
                    tm = fmaxf(tm, __shfl_xor(tm, off));
                const float mn = fmaxf(m_[rt][r], tm);
                const float al = exp2f(m_[rt][r] - mn);
                m_[rt][r] = mn;
                float psum = 0.f;
                #pragma unroll
                for (int nt = 0; nt < 4; nt++) {
                    const float pv = exp2f(s[rt][nt][r] - mn);
                    s[rt][nt][r] = pv;
                    psum += pv;
                }
                #pragma unroll
                for (int off = 1; off < 16; off <<= 1)
                    psum += __shfl_xor(psum, off);
                l_[rt][r] = l_[rt][r] * al + psum;
                #pragma unroll
                for (int ht = 0; ht < 4; ht++)
                    o[rt][ht][r] *= al;
            }
        }

        // P -> LDS (bf16) -> A-frags (within-wave, in-order DS, no barrier)
        #pragma unroll
        for (int rt = 0; rt < 2; rt++)
            #pragma unroll
            for (int nt = 0; nt < 4; nt++)
                #pragma unroll
                for (int r = 0; r < 4; r++)
                    ps[rt * 16 + g * 4 + r][nt * 16 + l15] = f2bf(s[rt][nt][r]);
        bf16x8 pf[2][2];
        #pragma unroll
        for (int rt = 0; rt < 2; rt++)
            #pragma unroll
            for (int jc = 0; jc < 2; jc++)
                pf[rt][jc] = *(const bf16x8*)&ps[rt * 16 + l15][jc * 32 + g * 8];

        // O += P V
        #pragma unroll
        for (int rt = 0; rt < 2; rt++)
            #pragma unroll
            for (int ht = 0; ht < 4; ht++)
                #pragma unroll
                for (int jc = 0; jc < 2; jc++)
                    o[rt][ht] = __builtin_amdgcn_mfma_f32_16x16x32_bf16(
                        pf[rt][jc], vf[ht][jc], o[rt][ht], 0, 0, 0);

        if (kt + 1 < nkv) {
            #pragma unroll
            for (int nt = 0; nt < 4; nt++)
                #pragma unroll
                for (int kc = 0; kc < 2; kc++)
                    kf[nt][kc] = kfn[nt][kc];
        }
    }

    // epilogue: out = O / l  (fp32, coalesced 64B segments)
    #pragma unroll
    for (int rt = 0; rt < 2; rt++)
        #pragma unroll
        for (int r = 0; r < 4; r++) {
            const float inv = 1.0f / l_[rt][r];
            #pragma unroll
            for (int ht = 0; ht < 4; ht++)
                out[((size_t)b * TT + r0 + rt * 16 + g * 4 + r) * 64 + ht * 16 + l15] =
                    o[rt][ht][r] * inv;
        }
}

extern "C" void kernel_launch(void* const* d_in, const int* in_sizes, int n_in,
                              void* d_out, int out_size, void* d_ws, size_t ws_size,
                              hipStream_t stream) {
    const float* x  = (const float*)d_in[0];
    const float* Wk = (const float*)d_in[1];
    const float* Wq = (const float*)d_in[2];
    const float* Wv = (const float*)d_in[3];
    float* outp = (float*)d_out;

    short* wt  = (short*)d_ws;                     // [192][1024] bf16
    short* qb  = wt + (size_t)192 * 1024;          // [16384][64] bf16 (pre-scaled)
    short* kb  = qb + (size_t)MROWS * 64;          // [16384][64] bf16
    short* vtb = kb + (size_t)MROWS * 64;          // [8][64][2048] bf16 (V^T)

    wtrans_kernel<<<48, 256, 0, stream>>>(Wk, Wq, Wv, wt);
    proj_kernel<<<MROWS / 64, 256, 0, stream>>>(x, wt, qb, kb, vtb);
    attn_kernel<<<BATCH * 64, 64, 0, stream>>>(qb, kb, vtb, outp);
}

// Round 3
// 71.618 us; speedup vs baseline: 3.8477x; 1.5918x over previous
//
#include <hip/hip_runtime.h>
#include <hip/hip_bf16.h>

#define TT 2048
#define BATCH 8
#define MROWS (BATCH*TT)   // 16384
#define AW 8               // waves per attn block

typedef __attribute__((ext_vector_type(8))) short bf16x8;   // MFMA A/B frag (4 VGPR)
typedef __attribute__((ext_vector_type(4))) short s16x4;
typedef __attribute__((ext_vector_type(4))) float f32x4;    // MFMA C/D frag

__device__ __forceinline__ short f2bf(float f) {
    union { __hip_bfloat16 h; short s; } u;
    u.h = __float2bfloat16(f);
    return u.s;
}
__device__ __forceinline__ float bf2f(short s) {
    union { unsigned u; float f; } u;
    u.u = ((unsigned)(unsigned short)s) << 16;
    return u.f;
}

// ---------------------------------------------------------------------------
// W transpose: Wq|Wk|Wv [1024][64] f32 -> wt [192][1024] bf16 (row n = col of W)
// Wq gets scale = (1/32)*log2(e) folded in (softmax scale + exp->exp2).
// ---------------------------------------------------------------------------
__global__ __launch_bounds__(256) void wtrans_kernel(
    const float* __restrict__ Wk, const float* __restrict__ Wq,
    const float* __restrict__ Wv, short* __restrict__ wt)
{
    __shared__ float tile[64][68];
    const int mat = blockIdx.x >> 4;           // 0=q,1=k,2=v
    const int k0  = (blockIdx.x & 15) * 64;
    const float* W = (mat == 0) ? Wq : (mat == 1) ? Wk : Wv;
    const float scl = (mat == 0) ? 0.04508422002778011f : 1.0f;  // (1/32)*log2(e)
    const int t = threadIdx.x;
    const int row = t >> 2, quad = t & 3;
    #pragma unroll
    for (int i = 0; i < 4; i++) {
        float4 v = *(const float4*)(W + (size_t)(k0 + row) * 64 + quad * 16 + i * 4);
        *(float4*)&tile[row][quad * 16 + i * 4] = v;
    }
    __syncthreads();
    short tmp[16];
    #pragma unroll
    for (int j = 0; j < 16; j++) tmp[j] = f2bf(tile[quad * 16 + j][row] * scl);
    short* dst = wt + (size_t)(mat * 64 + row) * 1024 + k0 + quad * 16;
    #pragma unroll
    for (int j2 = 0; j2 < 2; j2++) {
        bf16x8 o;
        #pragma unroll
        for (int jj = 0; jj < 8; jj++) o[jj] = tmp[j2 * 8 + jj];
        *(bf16x8*)(dst + j2 * 8) = o;
    }
}

// ---------------------------------------------------------------------------
// Projection: x[16384][1024] f32 -> q,k [16384][64] bf16, v^T [8][64][2048] bf16
// ---------------------------------------------------------------------------
__global__ __launch_bounds__(256) void proj_kernel(
    const float* __restrict__ x, const short* __restrict__ wt,
    short* __restrict__ qb, short* __restrict__ kb, short* __restrict__ vtb)
{
    __shared__ short xs[2][64][72];
    __shared__ short vsl[64][66];
    const int tid  = threadIdx.x;
    const int lane = tid & 63, w = tid >> 6;
    const int l15  = lane & 15, g = lane >> 4;
    const int r0   = blockIdx.x * 64;
    const int xrow = tid >> 2, xquad = tid & 3;

    f32x4 acc[4][3];
    #pragma unroll
    for (int rt = 0; rt < 4; rt++)
        #pragma unroll
        for (int nt = 0; nt < 3; nt++)
            acc[rt][nt] = (f32x4){0.f, 0.f, 0.f, 0.f};

    const float* xbase = x + (size_t)(r0 + xrow) * 1024 + xquad * 16;

    float4 xr[4];
    #pragma unroll
    for (int i = 0; i < 4; i++) xr[i] = *(const float4*)(xbase + i * 4);
    #pragma unroll
    for (int i = 0; i < 4; i++) {
        s16x4 s = { f2bf(xr[i].x), f2bf(xr[i].y), f2bf(xr[i].z), f2bf(xr[i].w) };
        *(s16x4*)&xs[0][xrow][xquad * 16 + i * 4] = s;
    }

    int cur = 0;
    for (int ks = 0; ks < 16; ks++) {
        const int k0 = ks * 64;
        if (ks < 15) {
            #pragma unroll
            for (int i = 0; i < 4; i++) xr[i] = *(const float4*)(xbase + k0 + 64 + i * 4);
        }
        bf16x8 bfrag[3][2];
        #pragma unroll
        for (int nt = 0; nt < 3; nt++)
            #pragma unroll
            for (int kc = 0; kc < 2; kc++)
                bfrag[nt][kc] = *(const bf16x8*)(
                    wt + (size_t)(w * 48 + nt * 16 + l15) * 1024 + k0 + kc * 32 + g * 8);
        __syncthreads();
        #pragma unroll
        for (int kc = 0; kc < 2; kc++) {
            bf16x8 af[4];
            #pragma unroll
            for (int rt = 0; rt < 4; rt++)
                af[rt] = *(const bf16x8*)&xs[cur][rt * 16 + l15][kc * 32 + g * 8];
            #pragma unroll
            for (int rt = 0; rt < 4; rt++)
                #pragma unroll
                for (int nt = 0; nt < 3; nt++)
                    acc[rt][nt] = __builtin_amdgcn_mfma_f32_16x16x32_bf16(
                        af[rt], bfrag[nt][kc], acc[rt][nt], 0, 0, 0);
        }
        if (ks < 15) {
            #pragma unroll
            for (int i = 0; i < 4; i++) {
                s16x4 s = { f2bf(xr[i].x), f2bf(xr[i].y), f2bf(xr[i].z), f2bf(xr[i].w) };
                *(s16x4*)&xs[cur ^ 1][xrow][xquad * 16 + i * 4] = s;
            }
        }
        cur ^= 1;
    }

    const int bi  = r0 >> 11;
    const int sl0 = r0 & 2047;
    #pragma unroll
    for (int rt = 0; rt < 4; rt++)
        #pragma unroll
        for (int nt = 0; nt < 3; nt++) {
            const int c = w * 48 + nt * 16 + l15;
            #pragma unroll
            for (int r = 0; r < 4; r++) {
                const int row = r0 + rt * 16 + g * 4 + r;
                const short v = f2bf(acc[rt][nt][r]);
                if (c < 64)        qb[(size_t)row * 64 + c] = v;
                else if (c < 128)  kb[(size_t)row * 64 + (c - 64)] = v;
                else               vsl[rt * 16 + g * 4 + r][c - 128] = v;
            }
        }
    __syncthreads();
    {
        const int h = tid >> 2, seg = tid & 3;
        short tmp[16];
        #pragma unroll
        for (int j = 0; j < 16; j++) tmp[j] = vsl[seg * 16 + j][h];
        short* dst = vtb + ((size_t)bi * 64 + h) * TT + sl0 + seg * 16;
        #pragma unroll
        for (int j2 = 0; j2 < 2; j2++) {
            bf16x8 o;
            #pragma unroll
            for (int jj = 0; jj < 8; jj++) o[jj] = tmp[j2 * 8 + jj];
            *(bf16x8*)(dst + j2 * 8) = o;
        }
    }
}

// ---------------------------------------------------------------------------
// Flash attention: 512 blocks x 8 waves. Wave w handles kv-tiles w, w+8, ...
// of its block's 32-row q-tile (max 4 tiles/wave -> balanced). Per-wave
// partial (m,l,O); merged through LDS at block end. All 512 blocks resident
// (2/CU) at 4 waves/SIMD -> latency overlap the single-wave version lacked.
// ---------------------------------------------------------------------------
__global__ __launch_bounds__(512, 4) void attn_kernel(
    const short* __restrict__ qb, const short* __restrict__ kb,
    const short* __restrict__ vtb, float* __restrict__ out)
{
    // per-wave 4608 B region: ps [32][72] bf16 during compute,
    // then pO [32][68] bf16 partial-O for the merge. ml = per-wave m/l.
    __shared__ __align__(16) char smem[AW * 4608];
    __shared__ float ml[AW][64];   // [w][0..31]=m, [w][32..63]=l

    const int tid  = threadIdx.x;
    const int w    = tid >> 6, lane = tid & 63;
    const int l15  = lane & 15, g = lane >> 4;
    const int b    = blockIdx.x & 7;
    const int qt   = 63 - (blockIdx.x >> 3);
    const int r0   = qt * 32;
    const int nkv  = (r0 >> 6) + 1;

    short* ps = (short*)(smem + w * 4608);   // [32][72]

    const short* q  = qb  + (size_t)b * TT * 64;
    const short* k  = kb  + (size_t)b * TT * 64;
    const short* vt = vtb + (size_t)b * 64 * TT;

    bf16x8 qf[2][2];
    #pragma unroll
    for (int rt = 0; rt < 2; rt++)
        #pragma unroll
        for (int kc = 0; kc < 2; kc++)
            qf[rt][kc] = *(const bf16x8*)(q + (size_t)(r0 + rt * 16 + l15) * 64 + kc * 32 + g * 8);

    f32x4 o[2][4];
    float m_[2][4], l_[2][4];
    #pragma unroll
    for (int rt = 0; rt < 2; rt++) {
        #pragma unroll
        for (int ht = 0; ht < 4; ht++) o[rt][ht] = (f32x4){0.f, 0.f, 0.f, 0.f};
        #pragma unroll
        for (int r = 0; r < 4; r++) { m_[rt][r] = -INFINITY; l_[rt][r] = 0.f; }
    }

    for (int t = w; t < nkv; t += AW) {
        const int s0 = t * 64;
        const bool diag = (t == nkv - 1);

        bf16x8 kf[4][2];
        #pragma unroll
        for (int nt = 0; nt < 4; nt++)
            #pragma unroll
            for (int kc = 0; kc < 2; kc++)
                kf[nt][kc] = *(const bf16x8*)(
                    k + (size_t)(s0 + nt * 16 + l15) * 64 + kc * 32 + g * 8);

        // ---- rt = 0: QK + softmax + P-write (keeps s-frag live range small)
        bf16x8 vf[4][2];
        #pragma unroll
        for (int rt = 0; rt < 2; rt++) {
            f32x4 s[4];
            #pragma unroll
            for (int nt = 0; nt < 4; nt++) s[nt] = (f32x4){0.f, 0.f, 0.f, 0.f};
            #pragma unroll
            for (int kc = 0; kc < 2; kc++)
                #pragma unroll
                for (int nt = 0; nt < 4; nt++)
                    s[nt] = __builtin_amdgcn_mfma_f32_16x16x32_bf16(
                        qf[rt][kc], kf[nt][kc], s[nt], 0, 0, 0);

            if (rt == 1) {   // issue V loads; latency hides under rt1 softmax
                #pragma unroll
                for (int ht = 0; ht < 4; ht++)
                    #pragma unroll
                    for (int jc = 0; jc < 2; jc++)
                        vf[ht][jc] = *(const bf16x8*)(
                            vt + (size_t)(ht * 16 + l15) * TT + s0 + jc * 32 + g * 8);
            }

            if (diag) {
                #pragma unroll
                for (int nt = 0; nt < 4; nt++) {
                    const int col = s0 + nt * 16 + l15;
                    #pragma unroll
                    for (int r = 0; r < 4; r++) {
                        const int row = r0 + rt * 16 + g * 4 + r;
                        if (col > row) s[nt][r] = -INFINITY;
                    }
                }
            }

            #pragma unroll
            for (int r = 0; r < 4; r++) {
                float tm = fmaxf(fmaxf(s[0][r], s[1][r]), fmaxf(s[2][r], s[3][r]));
                #pragma unroll
                for (int off = 1; off < 16; off <<= 1)
                    tm = fmaxf(tm, __shfl_xor(tm, off));
                const float mn = fmaxf(m_[rt][r], tm);
                const float al = exp2f(m_[rt][r] - mn);
                m_[rt][r] = mn;
                float psum = 0.f;
                #pragma unroll
                for (int nt = 0; nt < 4; nt++) {
                    const float pv = exp2f(s[nt][r] - mn);
                    s[nt][r] = pv;
                    psum += pv;
                }
                #pragma unroll
                for (int off = 1; off < 16; off <<= 1)
                    psum += __shfl_xor(psum, off);
                l_[rt][r] = l_[rt][r] * al + psum;
                #pragma unroll
                for (int ht = 0; ht < 4; ht++)
                    o[rt][ht][r] *= al;
            }

            #pragma unroll
            for (int nt = 0; nt < 4; nt++)
                #pragma unroll
                for (int r = 0; r < 4; r++)
                    ps[(rt * 16 + g * 4 + r) * 72 + nt * 16 + l15] = f2bf(s[nt][r]);
        }

        // ---- P@V
        bf16x8 pf[2][2];
        #pragma unroll
        for (int rt = 0; rt < 2; rt++)
            #pragma unroll
            for (int jc = 0; jc < 2; jc++)
                pf[rt][jc] = *(const bf16x8*)&ps[(rt * 16 + l15) * 72 + jc * 32 + g * 8];
        #pragma unroll
        for (int jc = 0; jc < 2; jc++)
            #pragma unroll
            for (int rt = 0; rt < 2; rt++)
                #pragma unroll
                for (int ht = 0; ht < 4; ht++)
                    o[rt][ht] = __builtin_amdgcn_mfma_f32_16x16x32_bf16(
                        pf[rt][jc], vf[ht][jc], o[rt][ht], 0, 0, 0);
    }

    // ---- write per-wave partials (m, l into ml; O as bf16 into pO)
    if (l15 == 0) {
        #pragma unroll
        for (int rt = 0; rt < 2; rt++)
            #pragma unroll
            for (int r = 0; r < 4; r++) {
                const int row = rt * 16 + g * 4 + r;
                ml[w][row]      = m_[rt][r];
                ml[w][32 + row] = l_[rt][r];
            }
    }
    short* pO = (short*)(smem + w * 4608);   // [32][68] bf16 (ps is dead now)
    #pragma unroll
    for (int rt = 0; rt < 2; rt++)
        #pragma unroll
        for (int ht = 0; ht < 4; ht++)
            #pragma unroll
            for (int r = 0; r < 4; r++)
                pO[(rt * 16 + g * 4 + r) * 68 + ht * 16 + l15] = f2bf(o[rt][ht][r]);
    __syncthreads();

    // ---- merge 8 partials: thread = (row, 16B col segment)
    {
        const int row = tid >> 4, seg = tid & 15;
        float gm = -INFINITY;
        #pragma unroll
        for (int w2 = 0; w2 < AW; w2++) gm = fmaxf(gm, ml[w2][row]);
        float accL = 0.f;
        float accO[4] = {0.f, 0.f, 0.f, 0.f};
        #pragma unroll
        for (int w2 = 0; w2 < AW; w2++) {
            const float sc = exp2f(ml[w2][row] - gm);
            accL = fmaf(sc, ml[w2][32 + row], accL);
            const s16x4 ov = *(const s16x4*)((const short*)(smem + w2 * 4608) + row * 68 + seg * 4);
            #pragma unroll
            for (int j = 0; j < 4; j++)
                accO[j] = fmaf(sc, bf2f(ov[j]), accO[j]);
        }
        const float inv = 1.f / accL;
        float4 res = make_float4(accO[0] * inv, accO[1] * inv, accO[2] * inv, accO[3] * inv);
        *(float4*)(out + ((size_t)b * TT + r0 + row) * 64 + seg * 4) = res;
    }
}

extern "C" void kernel_launch(void* const* d_in, const int* in_sizes, int n_in,
                              void* d_out, int out_size, void* d_ws, size_t ws_size,
                              hipStream_t stream) {
    const float* x  = (const float*)d_in[0];
    const float* Wk = (const float*)d_in[1];
    const float* Wq = (const float*)d_in[2];
    const float* Wv = (const float*)d_in[3];
    float* outp = (float*)d_out;

    short* wt  = (short*)d_ws;                     // [192][1024] bf16
    short* qb  = wt + (size_t)192 * 1024;          // [16384][64] bf16 (pre-scaled)
    short* kb  = qb + (size_t)MROWS * 64;          // [16384][64] bf16
    short* vtb = kb + (size_t)MROWS * 64;          // [8][64][2048] bf16 (V^T)

    wtrans_kernel<<<48, 256, 0, stream>>>(Wk, Wq, Wv, wt);
    proj_kernel<<<MROWS / 64, 256, 0, stream>>>(x, wt, qb, kb, vtb);
    attn_kernel<<<BATCH * 64, 512, 0, stream>>>(qb, kb, vtb, outp);
}

// Round 4
// 62.256 us; speedup vs baseline: 4.4263x; 1.1504x over previous
//
#include <hip/hip_runtime.h>
#include <hip/hip_bf16.h>

#define TT 2048
#define BATCH 8
#define MROWS (BATCH*TT)   // 16384
#define AW 8               // waves per attn block

typedef __attribute__((ext_vector_type(8))) short bf16x8;   // MFMA A/B frag (4 VGPR)
typedef __attribute__((ext_vector_type(4))) short s16x4;
typedef __attribute__((ext_vector_type(4))) float f32x4;    // MFMA C/D frag

__device__ __forceinline__ short f2bf(float f) {
    union { __hip_bfloat16 h; short s; } u;
    u.h = __float2bfloat16(f);
    return u.s;
}
__device__ __forceinline__ float bf2f(short s) {
    union { unsigned u; float f; } u;
    u.u = ((unsigned)(unsigned short)s) << 16;
    return u.f;
}

// ---------------------------------------------------------------------------
// W transpose: Wq|Wk|Wv [1024][64] f32 -> wt [192][1024] bf16 (row n = col of W)
// Wq gets scale = (1/32)*log2(e) folded in (softmax scale + exp->exp2).
// ---------------------------------------------------------------------------
__global__ __launch_bounds__(256) void wtrans_kernel(
    const float* __restrict__ Wk, const float* __restrict__ Wq,
    const float* __restrict__ Wv, short* __restrict__ wt)
{
    __shared__ float tile[64][68];
    const int mat = blockIdx.x >> 4;           // 0=q,1=k,2=v
    const int k0  = (blockIdx.x & 15) * 64;
    const float* W = (mat == 0) ? Wq : (mat == 1) ? Wk : Wv;
    const float scl = (mat == 0) ? 0.04508422002778011f : 1.0f;  // (1/32)*log2(e)
    const int t = threadIdx.x;
    const int row = t >> 2, quad = t & 3;
    #pragma unroll
    for (int i = 0; i < 4; i++) {
        float4 v = *(const float4*)(W + (size_t)(k0 + row) * 64 + quad * 16 + i * 4);
        *(float4*)&tile[row][quad * 16 + i * 4] = v;
    }
    __syncthreads();
    short tmp[16];
    #pragma unroll
    for (int j = 0; j < 16; j++) tmp[j] = f2bf(tile[quad * 16 + j][row] * scl);
    short* dst = wt + (size_t)(mat * 64 + row) * 1024 + k0 + quad * 16;
    #pragma unroll
    for (int j2 = 0; j2 < 2; j2++) {
        bf16x8 o;
        #pragma unroll
        for (int jj = 0; jj < 8; jj++) o[jj] = tmp[j2 * 8 + jj];
        *(bf16x8*)(dst + j2 * 8) = o;
    }
}

// ---------------------------------------------------------------------------
// Projection: x[16384][1024] f32 -> q,k [16384][64] bf16, v^T [8][64][2048] bf16
// ---------------------------------------------------------------------------
__global__ __launch_bounds__(256) void proj_kernel(
    const float* __restrict__ x, const short* __restrict__ wt,
    short* __restrict__ qb, short* __restrict__ kb, short* __restrict__ vtb)
{
    __shared__ short xs[2][64][72];
    __shared__ short vsl[64][66];
    const int tid  = threadIdx.x;
    const int lane = tid & 63, w = tid >> 6;
    const int l15  = lane & 15, g = lane >> 4;
    const int r0   = blockIdx.x * 64;
    const int xrow = tid >> 2, xquad = tid & 3;

    f32x4 acc[4][3];
    #pragma unroll
    for (int rt = 0; rt < 4; rt++)
        #pragma unroll
        for (int nt = 0; nt < 3; nt++)
            acc[rt][nt] = (f32x4){0.f, 0.f, 0.f, 0.f};

    const float* xbase = x + (size_t)(r0 + xrow) * 1024 + xquad * 16;

    float4 xr[4];
    #pragma unroll
    for (int i = 0; i < 4; i++) xr[i] = *(const float4*)(xbase + i * 4);
    #pragma unroll
    for (int i = 0; i < 4; i++) {
        s16x4 s = { f2bf(xr[i].x), f2bf(xr[i].y), f2bf(xr[i].z), f2bf(xr[i].w) };
        *(s16x4*)&xs[0][xrow][xquad * 16 + i * 4] = s;
    }

    int cur = 0;
    for (int ks = 0; ks < 16; ks++) {
        const int k0 = ks * 64;
        if (ks < 15) {
            #pragma unroll
            for (int i = 0; i < 4; i++) xr[i] = *(const float4*)(xbase + k0 + 64 + i * 4);
        }
        bf16x8 bfrag[3][2];
        #pragma unroll
        for (int nt = 0; nt < 3; nt++)
            #pragma unroll
            for (int kc = 0; kc < 2; kc++)
                bfrag[nt][kc] = *(const bf16x8*)(
                    wt + (size_t)(w * 48 + nt * 16 + l15) * 1024 + k0 + kc * 32 + g * 8);
        __syncthreads();
        #pragma unroll
        for (int kc = 0; kc < 2; kc++) {
            bf16x8 af[4];
            #pragma unroll
            for (int rt = 0; rt < 4; rt++)
                af[rt] = *(const bf16x8*)&xs[cur][rt * 16 + l15][kc * 32 + g * 8];
            #pragma unroll
            for (int rt = 0; rt < 4; rt++)
                #pragma unroll
                for (int nt = 0; nt < 3; nt++)
                    acc[rt][nt] = __builtin_amdgcn_mfma_f32_16x16x32_bf16(
                        af[rt], bfrag[nt][kc], acc[rt][nt], 0, 0, 0);
        }
        if (ks < 15) {
            #pragma unroll
            for (int i = 0; i < 4; i++) {
                s16x4 s = { f2bf(xr[i].x), f2bf(xr[i].y), f2bf(xr[i].z), f2bf(xr[i].w) };
                *(s16x4*)&xs[cur ^ 1][xrow][xquad * 16 + i * 4] = s;
            }
        }
        cur ^= 1;
    }

    const int bi  = r0 >> 11;
    const int sl0 = r0 & 2047;
    #pragma unroll
    for (int rt = 0; rt < 4; rt++)
        #pragma unroll
        for (int nt = 0; nt < 3; nt++) {
            const int c = w * 48 + nt * 16 + l15;
            #pragma unroll
            for (int r = 0; r < 4; r++) {
                const int row = r0 + rt * 16 + g * 4 + r;
                const short v = f2bf(acc[rt][nt][r]);
                if (c < 64)        qb[(size_t)row * 64 + c] = v;
                else if (c < 128)  kb[(size_t)row * 64 + (c - 64)] = v;
                else               vsl[rt * 16 + g * 4 + r][c - 128] = v;
            }
        }
    __syncthreads();
    {
        const int h = tid >> 2, seg = tid & 3;
        short tmp[16];
        #pragma unroll
        for (int j = 0; j < 16; j++) tmp[j] = vsl[seg * 16 + j][h];
        short* dst = vtb + ((size_t)bi * 64 + h) * TT + sl0 + seg * 16;
        #pragma unroll
        for (int j2 = 0; j2 < 2; j2++) {
            bf16x8 o;
            #pragma unroll
            for (int jj = 0; jj < 8; jj++) o[jj] = tmp[j2 * 8 + jj];
            *(bf16x8*)(dst + j2 * 8) = o;
        }
    }
}

// ---------------------------------------------------------------------------
// Flash attention v3: swapped QK^T (S^T = mfma(K,Q)) -> q-row is lane-local:
// softmax = in-register tree + 2 shfl_xor (vs 64 ds-swizzles). P written
// q-major (b64), read as contiguous b128 A-frags; PV uses B=V from vt layout.
// amdgpu_waves_per_eu(4,4) pins VGPR cap at 128 -> no spill-to-64 squeeze.
// 512 blocks x 8 waves, split-kv + LDS merge as before.
// ---------------------------------------------------------------------------
__global__ __attribute__((amdgpu_waves_per_eu(4, 4))) __launch_bounds__(512)
void attn_kernel(
    const short* __restrict__ qb, const short* __restrict__ kb,
    const short* __restrict__ vtb, float* __restrict__ out)
{
    // per-wave 4608 B region: ps [32][72] bf16 (P^T staging), then pO [32][68]
    __shared__ __align__(16) char smem[AW * 4608];
    __shared__ float ml[AW][64];   // [w][0..31]=m, [w][32..63]=l

    const int tid  = threadIdx.x;
    const int w    = tid >> 6, lane = tid & 63;
    const int l15  = lane & 15, g = lane >> 4;
    const int b    = blockIdx.x & 7;
    const int qt   = 63 - (blockIdx.x >> 3);
    const int r0   = qt * 32;
    const int nkv  = (r0 >> 6) + 1;

    short* ps = (short*)(smem + w * 4608);   // [32][72]

    const short* q  = qb  + (size_t)b * TT * 64;
    const short* k  = kb  + (size_t)b * TT * 64;
    const short* vt = vtb + (size_t)b * 64 * TT;

    // Q frags (B-operand of swapped QK): col = q-row = l15, contraction d
    bf16x8 qf[2][2];
    #pragma unroll
    for (int rt = 0; rt < 2; rt++)
        #pragma unroll
        for (int kc = 0; kc < 2; kc++)
            qf[rt][kc] = *(const bf16x8*)(q + (size_t)(r0 + rt * 16 + l15) * 64 + kc * 32 + g * 8);

    f32x4 o[2][4];
    float m_[2] = { -INFINITY, -INFINITY };
    float l_[2] = { 0.f, 0.f };
    #pragma unroll
    for (int rt = 0; rt < 2; rt++)
        #pragma unroll
        for (int ht = 0; ht < 4; ht++) o[rt][ht] = (f32x4){0.f, 0.f, 0.f, 0.f};

    for (int t = w; t < nkv; t += AW) {
        const int s0 = t * 64;
        const bool diag = (t == nkv - 1);

        // K frags (A-operand): row = k-row = l15 per nt-tile
        bf16x8 kf[4][2];
        #pragma unroll
        for (int nt = 0; nt < 4; nt++)
            #pragma unroll
            for (int kc = 0; kc < 2; kc++)
                kf[nt][kc] = *(const bf16x8*)(
                    k + (size_t)(s0 + nt * 16 + l15) * 64 + kc * 32 + g * 8);

        bf16x8 vf[4][2];
        #pragma unroll
        for (int rt = 0; rt < 2; rt++) {
            // S^T[k][q] = K · Q^T : lane owns q-row (l15), k-rows nt*16+g*4+r
            f32x4 s[4];
            #pragma unroll
            for (int nt = 0; nt < 4; nt++) s[nt] = (f32x4){0.f, 0.f, 0.f, 0.f};
            #pragma unroll
            for (int kc = 0; kc < 2; kc++)
                #pragma unroll
                for (int nt = 0; nt < 4; nt++)
                    s[nt] = __builtin_amdgcn_mfma_f32_16x16x32_bf16(
                        kf[nt][kc], qf[rt][kc], s[nt], 0, 0, 0);

            if (rt == 1) {   // V frag loads; latency hides under rt1 softmax
                #pragma unroll
                for (int ht = 0; ht < 4; ht++)
                    #pragma unroll
                    for (int kc = 0; kc < 2; kc++)
                        vf[ht][kc] = *(const bf16x8*)(
                            vt + (size_t)(ht * 16 + l15) * TT + s0 + kc * 32 + g * 8);
            }

            if (diag) {   // mask if k > q
                const int qg = r0 + rt * 16 + l15;
                #pragma unroll
                for (int nt = 0; nt < 4; nt++) {
                    #pragma unroll
                    for (int r = 0; r < 4; r++)
                        if (s0 + nt * 16 + g * 4 + r > qg) s[nt][r] = -INFINITY;
                }
            }

            // row-max: in-register tree over 16 + 2 shfl_xor (across g-groups)
            float a0 = fmaxf(fmaxf(s[0][0], s[0][1]), fmaxf(s[0][2], s[0][3]));
            float a1 = fmaxf(fmaxf(s[1][0], s[1][1]), fmaxf(s[1][2], s[1][3]));
            float a2 = fmaxf(fmaxf(s[2][0], s[2][1]), fmaxf(s[2][2], s[2][3]));
            float a3 = fmaxf(fmaxf(s[3][0], s[3][1]), fmaxf(s[3][2], s[3][3]));
            float tm = fmaxf(fmaxf(a0, a1), fmaxf(a2, a3));
            tm = fmaxf(tm, __shfl_xor(tm, 16));
            tm = fmaxf(tm, __shfl_xor(tm, 32));

            const float mn = fmaxf(m_[rt], tm);
            const float al = __builtin_amdgcn_exp2f(m_[rt] - mn);
            m_[rt] = mn;

            #pragma unroll
            for (int nt = 0; nt < 4; nt++)
                #pragma unroll
                for (int r = 0; r < 4; r++)
                    s[nt][r] = __builtin_amdgcn_exp2f(s[nt][r] - mn);

            float b0 = (s[0][0] + s[0][1]) + (s[0][2] + s[0][3]);
            float b1 = (s[1][0] + s[1][1]) + (s[1][2] + s[1][3]);
            float b2 = (s[2][0] + s[2][1]) + (s[2][2] + s[2][3]);
            float b3 = (s[3][0] + s[3][1]) + (s[3][2] + s[3][3]);
            float ts = (b0 + b1) + (b2 + b3);
            ts += __shfl_xor(ts, 16);
            ts += __shfl_xor(ts, 32);
            l_[rt] = l_[rt] * al + ts;

            // rescale O (rows q = g*4+r): fetch al from lane l15' = g*4+r
            float ab[4];
            #pragma unroll
            for (int r = 0; r < 4; r++) ab[r] = __shfl(al, g * 4 + r);
            #pragma unroll
            for (int ht = 0; ht < 4; ht++)
                #pragma unroll
                for (int r = 0; r < 4; r++)
                    o[rt][ht][r] *= ab[r];

            // P write: q-major row rt*16+l15, 4 consecutive k per nt (b64)
            #pragma unroll
            for (int nt = 0; nt < 4; nt++) {
                s16x4 pk = { f2bf(s[nt][0]), f2bf(s[nt][1]),
                             f2bf(s[nt][2]), f2bf(s[nt][3]) };
                *(s16x4*)&ps[(rt * 16 + l15) * 72 + nt * 16 + g * 4] = pk;
            }
        }

        // O += P V : A = P (row=q=l15, contiguous b128), B = V (col=d=l15)
        bf16x8 pf[2][2];
        #pragma unroll
        for (int rt = 0; rt < 2; rt++)
            #pragma unroll
            for (int kc = 0; kc < 2; kc++)
                pf[rt][kc] = *(const bf16x8*)&ps[(rt * 16 + l15) * 72 + kc * 32 + g * 8];
        #pragma unroll
        for (int kc = 0; kc < 2; kc++)
            #pragma unroll
            for (int rt = 0; rt < 2; rt++)
                #pragma unroll
                for (int ht = 0; ht < 4; ht++)
                    o[rt][ht] = __builtin_amdgcn_mfma_f32_16x16x32_bf16(
                        pf[rt][kc], vf[ht][kc], o[rt][ht], 0, 0, 0);
    }

    // ---- write per-wave partials
    if (g == 0) {
        #pragma unroll
        for (int rt = 0; rt < 2; rt++) {
            ml[w][rt * 16 + l15]      = m_[rt];
            ml[w][32 + rt * 16 + l15] = l_[rt];
        }
    }
    short* pO = ps;   // [32][68] bf16 (ps is dead now)
    #pragma unroll
    for (int rt = 0; rt < 2; rt++)
        #pragma unroll
        for (int ht = 0; ht < 4; ht++)
            #pragma unroll
            for (int r = 0; r < 4; r++)
                pO[(rt * 16 + g * 4 + r) * 68 + ht * 16 + l15] = f2bf(o[rt][ht][r]);
    __syncthreads();

    // ---- merge 8 partials: thread = (row, 16B col segment)
    {
        const int row = tid >> 4, seg = tid & 15;
        float gm = -INFINITY;
        #pragma unroll
        for (int w2 = 0; w2 < AW; w2++) gm = fmaxf(gm, ml[w2][row]);
        float accL = 0.f;
        float accO[4] = {0.f, 0.f, 0.f, 0.f};
        #pragma unroll
        for (int w2 = 0; w2 < AW; w2++) {
            const float sc = __builtin_amdgcn_exp2f(ml[w2][row] - gm);
            accL = fmaf(sc, ml[w2][32 + row], accL);
            const s16x4 ov = *(const s16x4*)((const short*)(smem + w2 * 4608) + row * 68 + seg * 4);
            #pragma unroll
            for (int j = 0; j < 4; j++)
                accO[j] = fmaf(sc, bf2f(ov[j]), accO[j]);
        }
        const float inv = 1.f / accL;
        float4 res = make_float4(accO[0] * inv, accO[1] * inv, accO[2] * inv, accO[3] * inv);
        *(float4*)(out + ((size_t)b * TT + r0 + row) * 64 + seg * 4) = res;
    }
}

extern "C" void kernel_launch(void* const* d_in, const int* in_sizes, int n_in,
                              void* d_out, int out_size, void* d_ws, size_t ws_size,
                              hipStream_t stream) {
    const float* x  = (const float*)d_in[0];
    const float* Wk = (const float*)d_in[1];
    const float* Wq = (const float*)d_in[2];
    const float* Wv = (const float*)d_in[3];
    float* outp = (float*)d_out;

    short* wt  = (short*)d_ws;                     // [192][1024] bf16
    short* qb  = wt + (size_t)192 * 1024;          // [16384][64] bf16 (pre-scaled)
    short* kb  = qb + (size_t)MROWS * 64;          // [16384][64] bf16
    short* vtb = kb + (size_t)MROWS * 64;          // [8][64][2048] bf16 (V^T)

    wtrans_kernel<<<48, 256, 0, stream>>>(Wk, Wq, Wv, wt);
    proj_kernel<<<MROWS / 64, 256, 0, stream>>>(x, wt, qb, kb, vtb);
    attn_kernel<<<BATCH * 64, 512, 0, stream>>>(qb, kb, vtb, outp);
}

// Round 5
// 60.134 us; speedup vs baseline: 4.5825x; 1.0353x over previous
//
#include <hip/hip_runtime.h>
#include <hip/hip_bf16.h>

#define TT 2048
#define BATCH 8
#define MROWS (BATCH*TT)   // 16384
#define AW 8               // waves per attn block

typedef __attribute__((ext_vector_type(8))) short bf16x8;   // MFMA A/B frag (4 VGPR)
typedef __attribute__((ext_vector_type(4))) short s16x4;
typedef __attribute__((ext_vector_type(4))) float f32x4;    // MFMA C/D frag

__device__ __forceinline__ short f2bf(float f) {
    union { __hip_bfloat16 h; short s; } u;
    u.h = __float2bfloat16(f);
    return u.s;
}
__device__ __forceinline__ float bf2f(short s) {
    union { unsigned u; float f; } u;
    u.u = ((unsigned)(unsigned short)s) << 16;
    return u.f;
}

// ---------------------------------------------------------------------------
// W transpose: Wq|Wk|Wv [1024][64] f32 -> wt [192][1024] bf16 (row n = col of W)
// Wq gets scale = (1/32)*log2(e) folded in (softmax scale + exp->exp2).
// ---------------------------------------------------------------------------
__global__ __launch_bounds__(256) void wtrans_kernel(
    const float* __restrict__ Wk, const float* __restrict__ Wq,
    const float* __restrict__ Wv, short* __restrict__ wt)
{
    __shared__ float tile[64][68];
    const int mat = blockIdx.x >> 4;           // 0=q,1=k,2=v
    const int k0  = (blockIdx.x & 15) * 64;
    const float* W = (mat == 0) ? Wq : (mat == 1) ? Wk : Wv;
    const float scl = (mat == 0) ? 0.04508422002778011f : 1.0f;  // (1/32)*log2(e)
    const int t = threadIdx.x;
    const int row = t >> 2, quad = t & 3;
    #pragma unroll
    for (int i = 0; i < 4; i++) {
        float4 v = *(const float4*)(W + (size_t)(k0 + row) * 64 + quad * 16 + i * 4);
        *(float4*)&tile[row][quad * 16 + i * 4] = v;
    }
    __syncthreads();
    short tmp[16];
    #pragma unroll
    for (int j = 0; j < 16; j++) tmp[j] = f2bf(tile[quad * 16 + j][row] * scl);
    short* dst = wt + (size_t)(mat * 64 + row) * 1024 + k0 + quad * 16;
    #pragma unroll
    for (int j2 = 0; j2 < 2; j2++) {
        bf16x8 o;
        #pragma unroll
        for (int jj = 0; jj < 8; jj++) o[jj] = tmp[j2 * 8 + jj];
        *(bf16x8*)(dst + j2 * 8) = o;
    }
}

// ---------------------------------------------------------------------------
// Projection v2: x[16384][1024] f32 -> q,k [16384][64] bf16, v^T [8][64][2048]
// BM=32 rows/block -> 512 blocks (2/CU) so two blocks' serial k-loops overlap.
// 4 waves, wave w owns cols [w*48, w*48+48). Double-buffered LDS x staging.
// ---------------------------------------------------------------------------
__global__ __launch_bounds__(256) void proj_kernel(
    const float* __restrict__ x, const short* __restrict__ wt,
    short* __restrict__ qb, short* __restrict__ kb, short* __restrict__ vtb)
{
    __shared__ short xs[2][32][72];
    __shared__ short vsl[32][66];
    const int tid  = threadIdx.x;
    const int lane = tid & 63, w = tid >> 6;
    const int l15  = lane & 15, g = lane >> 4;
    const int r0   = blockIdx.x * 32;
    const int xrow = tid >> 3, xseg = tid & 7;   // row 0..31, 8-col segment

    f32x4 acc[2][3];
    #pragma unroll
    for (int rt = 0; rt < 2; rt++)
        #pragma unroll
        for (int nt = 0; nt < 3; nt++)
            acc[rt][nt] = (f32x4){0.f, 0.f, 0.f, 0.f};

    const float* xbase = x + (size_t)(r0 + xrow) * 1024 + xseg * 8;

    // prologue: stage k-tile 0 into buffer 0
    float4 xa = *(const float4*)(xbase);
    float4 xb = *(const float4*)(xbase + 4);
    {
        s16x4 sa = { f2bf(xa.x), f2bf(xa.y), f2bf(xa.z), f2bf(xa.w) };
        s16x4 sb = { f2bf(xb.x), f2bf(xb.y), f2bf(xb.z), f2bf(xb.w) };
        *(s16x4*)&xs[0][xrow][xseg * 8]     = sa;
        *(s16x4*)&xs[0][xrow][xseg * 8 + 4] = sb;
    }

    int cur = 0;
    for (int ks = 0; ks < 16; ks++) {
        const int k0 = ks * 64;
        if (ks < 15) {   // issue next x tile loads early; hide under MFMAs
            xa = *(const float4*)(xbase + k0 + 64);
            xb = *(const float4*)(xbase + k0 + 68);
        }
        bf16x8 bfrag[3][2];
        #pragma unroll
        for (int nt = 0; nt < 3; nt++)
            #pragma unroll
            for (int kc = 0; kc < 2; kc++)
                bfrag[nt][kc] = *(const bf16x8*)(
                    wt + (size_t)(w * 48 + nt * 16 + l15) * 1024 + k0 + kc * 32 + g * 8);
        __syncthreads();
        #pragma unroll
        for (int kc = 0; kc < 2; kc++) {
            bf16x8 af[2];
            #pragma unroll
            for (int rt = 0; rt < 2; rt++)
                af[rt] = *(const bf16x8*)&xs[cur][rt * 16 + l15][kc * 32 + g * 8];
            #pragma unroll
            for (int rt = 0; rt < 2; rt++)
                #pragma unroll
                for (int nt = 0; nt < 3; nt++)
                    acc[rt][nt] = __builtin_amdgcn_mfma_f32_16x16x32_bf16(
                        af[rt], bfrag[nt][kc], acc[rt][nt], 0, 0, 0);
        }
        if (ks < 15) {   // write next tile into the other buffer
            s16x4 sa = { f2bf(xa.x), f2bf(xa.y), f2bf(xa.z), f2bf(xa.w) };
            s16x4 sb = { f2bf(xb.x), f2bf(xb.y), f2bf(xb.z), f2bf(xb.w) };
            *(s16x4*)&xs[cur ^ 1][xrow][xseg * 8]     = sa;
            *(s16x4*)&xs[cur ^ 1][xrow][xseg * 8 + 4] = sb;
        }
        cur ^= 1;
    }

    const int bi  = r0 >> 11;
    const int sl0 = r0 & 2047;
    #pragma unroll
    for (int rt = 0; rt < 2; rt++)
        #pragma unroll
        for (int nt = 0; nt < 3; nt++) {
            const int c = w * 48 + nt * 16 + l15;
            #pragma unroll
            for (int r = 0; r < 4; r++) {
                const int row = r0 + rt * 16 + g * 4 + r;
                const short v = f2bf(acc[rt][nt][r]);
                if (c < 64)        qb[(size_t)row * 64 + c] = v;
                else if (c < 128)  kb[(size_t)row * 64 + (c - 64)] = v;
                else               vsl[rt * 16 + g * 4 + r][c - 128] = v;
            }
        }
    __syncthreads();
    {   // vt[b][h][seq] cooperative write: thread owns (h, 8-seq segment)
        const int h = tid >> 2, seg = tid & 3;
        short tmp[8];
        #pragma unroll
        for (int j = 0; j < 8; j++) tmp[j] = vsl[seg * 8 + j][h];
        bf16x8 o;
        #pragma unroll
        for (int jj = 0; jj < 8; jj++) o[jj] = tmp[jj];
        *(bf16x8*)(vtb + ((size_t)bi * 64 + h) * TT + sl0 + seg * 8) = o;
    }
}

// ---------------------------------------------------------------------------
// Flash attention v5: swapped QK^T + in-register softmax, split-kv over 8
// waves with LDS merge (as v4), plus: plain launch_bounds (VGPR headroom ->
// no AGPR-move tax on softmax) and software pipelining (V(t) + K(t+8) loads
// issued before softmax so their latency hides under it).
// ---------------------------------------------------------------------------
__global__ __launch_bounds__(512, 2)
void attn_kernel(
    const short* __restrict__ qb, const short* __restrict__ kb,
    const short* __restrict__ vtb, float* __restrict__ out)
{
    // per-wave 4608 B region: ps [32][72] bf16 (P staging), then pO [32][68]
    __shared__ __align__(16) char smem[AW * 4608];
    __shared__ float ml[AW][64];   // [w][0..31]=m, [w][32..63]=l

    const int tid  = threadIdx.x;
    const int w    = tid >> 6, lane = tid & 63;
    const int l15  = lane & 15, g = lane >> 4;
    const int b    = blockIdx.x & 7;
    const int qt   = 63 - (blockIdx.x >> 3);
    const int r0   = qt * 32;
    const int nkv  = (r0 >> 6) + 1;

    short* ps = (short*)(smem + w * 4608);   // [32][72]

    const short* q  = qb  + (size_t)b * TT * 64;
    const short* k  = kb  + (size_t)b * TT * 64;
    const short* vt = vtb + (size_t)b * 64 * TT;

    // Q frags (B-operand of swapped QK): col = q-row = l15
    bf16x8 qf[2][2];
    #pragma unroll
    for (int rt = 0; rt < 2; rt++)
        #pragma unroll
        for (int kc = 0; kc < 2; kc++)
            qf[rt][kc] = *(const bf16x8*)(q + (size_t)(r0 + rt * 16 + l15) * 64 + kc * 32 + g * 8);

    f32x4 o[2][4];
    float m_[2] = { -INFINITY, -INFINITY };
    float l_[2] = { 0.f, 0.f };
    #pragma unroll
    for (int rt = 0; rt < 2; rt++)
        #pragma unroll
        for (int ht = 0; ht < 4; ht++) o[rt][ht] = (f32x4){0.f, 0.f, 0.f, 0.f};

    // prologue: K frags for this wave's first tile
    bf16x8 kf[4][2];
    if (w < nkv) {
        #pragma unroll
        for (int nt = 0; nt < 4; nt++)
            #pragma unroll
            for (int kc = 0; kc < 2; kc++)
                kf[nt][kc] = *(const bf16x8*)(
                    k + (size_t)(w * 64 + nt * 16 + l15) * 64 + kc * 32 + g * 8);
    }

    for (int t = w; t < nkv; t += AW) {
        const int s0 = t * 64;
        const bool diag = (t == nkv - 1);
        const bool more = (t + AW < nkv);

        // S^T = K Q^T : lane owns q-row (l15); k-rows nt*16+g*4+r
        f32x4 s[2][4];
        #pragma unroll
        for (int rt = 0; rt < 2; rt++)
            #pragma unroll
            for (int nt = 0; nt < 4; nt++) s[rt][nt] = (f32x4){0.f, 0.f, 0.f, 0.f};
        #pragma unroll
        for (int kc = 0; kc < 2; kc++)
            #pragma unroll
            for (int rt = 0; rt < 2; rt++)
                #pragma unroll
                for (int nt = 0; nt < 4; nt++)
                    s[rt][nt] = __builtin_amdgcn_mfma_f32_16x16x32_bf16(
                        kf[nt][kc], qf[rt][kc], s[rt][nt], 0, 0, 0);

        // issue V(t) and prefetch K(t+8) NOW; latency hides under softmax
        bf16x8 vf[4][2];
        #pragma unroll
        for (int ht = 0; ht < 4; ht++)
            #pragma unroll
            for (int kc = 0; kc < 2; kc++)
                vf[ht][kc] = *(const bf16x8*)(
                    vt + (size_t)(ht * 16 + l15) * TT + s0 + kc * 32 + g * 8);
        bf16x8 kfn[4][2];
        if (more) {
            #pragma unroll
            for (int nt = 0; nt < 4; nt++)
                #pragma unroll
                for (int kc = 0; kc < 2; kc++)
                    kfn[nt][kc] = *(const bf16x8*)(
                        k + (size_t)(s0 + AW * 64 + nt * 16 + l15) * 64 + kc * 32 + g * 8);
        }

        if (diag) {   // mask if k > q (only the diagonal tile)
            #pragma unroll
            for (int rt = 0; rt < 2; rt++) {
                const int qg = r0 + rt * 16 + l15;
                #pragma unroll
                for (int nt = 0; nt < 4; nt++)
                    #pragma unroll
                    for (int r = 0; r < 4; r++)
                        if (s0 + nt * 16 + g * 4 + r > qg) s[rt][nt][r] = -INFINITY;
            }
        }

        // online softmax, in-register (q-row lane-local; 2 shfl_xor per rt)
        #pragma unroll
        for (int rt = 0; rt < 2; rt++) {
            float a0 = fmaxf(fmaxf(s[rt][0][0], s[rt][0][1]), fmaxf(s[rt][0][2], s[rt][0][3]));
            float a1 = fmaxf(fmaxf(s[rt][1][0], s[rt][1][1]), fmaxf(s[rt][1][2], s[rt][1][3]));
            float a2 = fmaxf(fmaxf(s[rt][2][0], s[rt][2][1]), fmaxf(s[rt][2][2], s[rt][2][3]));
            float a3 = fmaxf(fmaxf(s[rt][3][0], s[rt][3][1]), fmaxf(s[rt][3][2], s[rt][3][3]));
            float tm = fmaxf(fmaxf(a0, a1), fmaxf(a2, a3));
            tm = fmaxf(tm, __shfl_xor(tm, 16));
            tm = fmaxf(tm, __shfl_xor(tm, 32));

            const float mn = fmaxf(m_[rt], tm);
            const float al = __builtin_amdgcn_exp2f(m_[rt] - mn);
            m_[rt] = mn;

            #pragma unroll
            for (int nt = 0; nt < 4; nt++)
                #pragma unroll
                for (int r = 0; r < 4; r++)
                    s[rt][nt][r] = __builtin_amdgcn_exp2f(s[rt][nt][r] - mn);

            float b0 = (s[rt][0][0] + s[rt][0][1]) + (s[rt][0][2] + s[rt][0][3]);
            float b1 = (s[rt][1][0] + s[rt][1][1]) + (s[rt][1][2] + s[rt][1][3]);
            float b2 = (s[rt][2][0] + s[rt][2][1]) + (s[rt][2][2] + s[rt][2][3]);
            float b3 = (s[rt][3][0] + s[rt][3][1]) + (s[rt][3][2] + s[rt][3][3]);
            float ts = (b0 + b1) + (b2 + b3);
            ts += __shfl_xor(ts, 16);
            ts += __shfl_xor(ts, 32);
            l_[rt] = l_[rt] * al + ts;

            // rescale O (rows q = g*4+r): fetch al from lane g*4+r
            float ab[4];
            #pragma unroll
            for (int r = 0; r < 4; r++) ab[r] = __shfl(al, g * 4 + r);
            #pragma unroll
            for (int ht = 0; ht < 4; ht++)
                #pragma unroll
                for (int r = 0; r < 4; r++)
                    o[rt][ht][r] *= ab[r];

            // P write: q-major row rt*16+l15, 4 consecutive k per nt (b64)
            #pragma unroll
            for (int nt = 0; nt < 4; nt++) {
                s16x4 pk = { f2bf(s[rt][nt][0]), f2bf(s[rt][nt][1]),
                             f2bf(s[rt][nt][2]), f2bf(s[rt][nt][3]) };
                *(s16x4*)&ps[(rt * 16 + l15) * 72 + nt * 16 + g * 4] = pk;
            }
        }

        // O += P V : A = P (row=q=l15, contiguous b128), B = V (col=d=l15)
        bf16x8 pf[2][2];
        #pragma unroll
        for (int rt = 0; rt < 2; rt++)
            #pragma unroll
            for (int kc = 0; kc < 2; kc++)
                pf[rt][kc] = *(const bf16x8*)&ps[(rt * 16 + l15) * 72 + kc * 32 + g * 8];
        #pragma unroll
        for (int kc = 0; kc < 2; kc++)
            #pragma unroll
            for (int rt = 0; rt < 2; rt++)
                #pragma unroll
                for (int ht = 0; ht < 4; ht++)
                    o[rt][ht] = __builtin_amdgcn_mfma_f32_16x16x32_bf16(
                        pf[rt][kc], vf[ht][kc], o[rt][ht], 0, 0, 0);

        if (more) {
            #pragma unroll
            for (int nt = 0; nt < 4; nt++)
                #pragma unroll
                for (int kc = 0; kc < 2; kc++)
                    kf[nt][kc] = kfn[nt][kc];
        }
    }

    // ---- write per-wave partials
    if (g == 0) {
        #pragma unroll
        for (int rt = 0; rt < 2; rt++) {
            ml[w][rt * 16 + l15]      = m_[rt];
            ml[w][32 + rt * 16 + l15] = l_[rt];
        }
    }
    short* pO = ps;   // [32][68] bf16 (ps is dead now)
    #pragma unroll
    for (int rt = 0; rt < 2; rt++)
        #pragma unroll
        for (int ht = 0; ht < 4; ht++)
            #pragma unroll
            for (int r = 0; r < 4; r++)
                pO[(rt * 16 + g * 4 + r) * 68 + ht * 16 + l15] = f2bf(o[rt][ht][r]);
    __syncthreads();

    // ---- merge 8 partials: thread = (row, 16B col segment)
    {
        const int row = tid >> 4, seg = tid & 15;
        float gm = -INFINITY;
        #pragma unroll
        for (int w2 = 0; w2 < AW; w2++) gm = fmaxf(gm, ml[w2][row]);
        float accL = 0.f;
        float accO[4] = {0.f, 0.f, 0.f, 0.f};
        #pragma unroll
        for (int w2 = 0; w2 < AW; w2++) {
            const float sc = __builtin_amdgcn_exp2f(ml[w2][row] - gm);
            accL = fmaf(sc, ml[w2][32 + row], accL);
            const s16x4 ov = *(const s16x4*)((const short*)(smem + w2 * 4608) + row * 68 + seg * 4);
            #pragma unroll
            for (int j = 0; j < 4; j++)
                accO[j] = fmaf(sc, bf2f(ov[j]), accO[j]);
        }
        const float inv = 1.f / accL;
        float4 res = make_float4(accO[0] * inv, accO[1] * inv, accO[2] * inv, accO[3] * inv);
        *(float4*)(out + ((size_t)b * TT + r0 + row) * 64 + seg * 4) = res;
    }
}

extern "C" void kernel_launch(void* const* d_in, const int* in_sizes, int n_in,
                              void* d_out, int out_size, void* d_ws, size_t ws_size,
                              hipStream_t stream) {
    const float* x  = (const float*)d_in[0];
    const float* Wk = (const float*)d_in[1];
    const float* Wq = (const float*)d_in[2];
    const float* Wv = (const float*)d_in[3];
    float* outp = (float*)d_out;

    short* wt  = (short*)d_ws;                     // [192][1024] bf16
    short* qb  = wt + (size_t)192 * 1024;          // [16384][64] bf16 (pre-scaled)
    short* kb  = qb + (size_t)MROWS * 64;          // [16384][64] bf16
    short* vtb = kb + (size_t)MROWS * 64;          // [8][64][2048] bf16 (V^T)

    wtrans_kernel<<<48, 256, 0, stream>>>(Wk, Wq, Wv, wt);
    proj_kernel<<<MROWS / 32, 256, 0, stream>>>(x, wt, qb, kb, vtb);
    attn_kernel<<<BATCH * 64, 512, 0, stream>>>(qb, kb, vtb, outp);
}